// Round 6
// baseline (191.144 us; speedup 1.0000x reference)
//
#include <hip/hip_runtime.h>
#include <math.h>

#define NB     32
#define FH     11
#define FW     20
#define CIN    512
#define CMID   1024
#define NANG   17
#define NPREDD 77
#define NEDGE  42
#define NPROPP 714
#define NOFF   72
#define NCLS   34
#define NREGR  1241
#define N2PAD  1280
#define MTOT   1344      // NB * NEDGE
#define NSTRIPSF 71.0f
#define PADK   40        // padded LDS row length in bf16 units (2-way-only b128 reads)

typedef unsigned long long u64;
typedef unsigned short ushortt;
typedef short s8v __attribute__((ext_vector_type(8)));
typedef ushortt u4v __attribute__((ext_vector_type(4)));
typedef float f4v __attribute__((ext_vector_type(4)));

__device__ inline ushortt f2bf(float f) {          // RNE fp32 -> bf16
    unsigned u = __float_as_uint(f);
    u += 0x7fffu + ((u >> 16) & 1u);
    return (ushortt)(u >> 16);
}
__device__ inline float bf2f(ushortt h) {
    return __uint_as_float(((unsigned)h) << 16);
}

// ------------- prep: coalesced LDS-transpose gather + pre-split ALL weights hi/lo ---
__global__ __launch_bounds__(256) void k_prep(const float* __restrict__ feat,
                                              ushortt* __restrict__ A1hi,
                                              ushortt* __restrict__ A1lo,
                                              const float* __restrict__ Wconv,
                                              ushortt* __restrict__ B1h,
                                              ushortt* __restrict__ B1l,
                                              const float* __restrict__ Wcls,
                                              const float* __restrict__ Wreg,
                                              ushortt* __restrict__ B2h,
                                              ushortt* __restrict__ B2l)
{
    __shared__ unsigned T[32 * 221];               // packed (hi|lo<<16), row pad 221 (conflict-free)
    int bid = blockIdx.x, tid = threadIdx.x;
    if (bid < 512) {
        int p0 = bid * 32;                         // first (b,c) plane, 32 planes/block, same b
        int b  = p0 >> 9;
        int c0 = p0 & 511;
        const float* fp = feat + (size_t)p0 * 220;
        for (int i = tid; i < 32 * 220; i += 256) {      // fully coalesced read of 32 planes
            float v = fp[i];
            int pl = i / 220, off = i - pl * 220;
            ushortt hi = f2bf(v);
            ushortt lo = f2bf(v - bf2f(hi));
            T[pl * 221 + off] = ((unsigned)hi) | (((unsigned)lo) << 16);
        }
        __syncthreads();
        int cl = tid & 31;
        for (int e = tid >> 5; e < NEDGE; e += 8) {      // 64B-burst writes into A1
            int hw = (e < FH) ? e * FW
                   : (e < 2 * FH) ? (e - FH) * FW + (FW - 1)
                   : (FH - 1) * FW + (e - 2 * FH);
            unsigned u = T[cl * 221 + hw];
            size_t o = (size_t)(b * NEDGE + e) * CIN + c0 + cl;
            A1hi[o] = (ushortt)(u & 0xffffu);
            A1lo[o] = (ushortt)(u >> 16);
        }
    } else if (bid < 1024) {
        int t = (bid - 512) * 256 + tid;           // 131072 threads x 4 elems
        float4 v = *(const float4*)(Wconv + (size_t)t * 4);
        float vf[4] = {v.x, v.y, v.z, v.w};
        u4v hv, lv;
#pragma unroll
        for (int j = 0; j < 4; ++j) {
            ushortt h = f2bf(vf[j]);
            hv[j] = h;
            lv[j] = f2bf(vf[j] - bf2f(h));
        }
        *(u4v*)(B1h + (size_t)t * 4) = hv;
        *(u4v*)(B1l + (size_t)t * 4) = lv;
    } else {
        int t = (bid - 1024) * 256 + tid;          // 327680 threads x 4 elems
        int row = t >> 8, col = (t & 255) * 4;
        float4 v = make_float4(0.f, 0.f, 0.f, 0.f);
        if (row < NCLS)              v = *(const float4*)(Wcls + (size_t)row * CMID + col);
        else if (row < NCLS + NREGR) v = *(const float4*)(Wreg + (size_t)(row - NCLS) * CMID + col);
        float vf[4] = {v.x, v.y, v.z, v.w};
        u4v hv, lv;
#pragma unroll
        for (int j = 0; j < 4; ++j) {
            ushortt h = f2bf(vf[j]);
            hv[j] = h;
            lv[j] = f2bf(vf[j] - bf2f(h));
        }
        *(u4v*)(B2h + (size_t)t * 4) = hv;
        *(u4v*)(B2l + (size_t)t * 4) = lv;
    }
}

// ===== 128x64-tile MFMA GEMM machinery (4 waves: wm in {0,64}, wn in {0,32}) =====
// one k-step: ds_read fragments from LDS buffer BUF + 32 MFMA (4-product hi/lo emu)
#define GEMM_STEP(BUF)                                                               \
    {                                                                                \
        s8v ah[4], al[4], bh[2], bl[2];                                              \
        _Pragma("unroll")                                                            \
        for (int s = 0; s < 4; ++s) {                                                \
            ah[s] = *(const s8v*)&Ash[BUF][(wm + s * 16 + l15) * PADK + quad * 8];   \
            al[s] = *(const s8v*)&Asl[BUF][(wm + s * 16 + l15) * PADK + quad * 8];   \
        }                                                                            \
        _Pragma("unroll")                                                            \
        for (int s = 0; s < 2; ++s) {                                                \
            bh[s] = *(const s8v*)&Bsh[BUF][(wn + s * 16 + l15) * PADK + quad * 8];   \
            bl[s] = *(const s8v*)&Bsl[BUF][(wn + s * 16 + l15) * PADK + quad * 8];   \
        }                                                                            \
        _Pragma("unroll")                                                            \
        for (int sm = 0; sm < 4; ++sm)                                               \
            _Pragma("unroll")                                                        \
            for (int sn = 0; sn < 2; ++sn) {                                         \
                acc[sm][sn] = __builtin_amdgcn_mfma_f32_16x16x32_bf16(al[sm], bl[sn], acc[sm][sn], 0, 0, 0); \
                acc[sm][sn] = __builtin_amdgcn_mfma_f32_16x16x32_bf16(al[sm], bh[sn], acc[sm][sn], 0, 0, 0); \
                acc[sm][sn] = __builtin_amdgcn_mfma_f32_16x16x32_bf16(ah[sm], bl[sn], acc[sm][sn], 0, 0, 0); \
                acc[sm][sn] = __builtin_amdgcn_mfma_f32_16x16x32_bf16(ah[sm], bh[sn], acc[sm][sn], 0, 0, 0); \
            }                                                                        \
    }

// A rows srow and srow+64 (m-tile 128), B row srow (n-tile 64)
#define LOADSET(A, A2, L, L2, Bv, Cv, OFF)                                           \
    A  = *(const s8v*)(Ahp  + (OFF));                                                \
    A2 = *(const s8v*)(Ahp2 + (OFF));                                                \
    L  = *(const s8v*)(Alp  + (OFF));                                                \
    L2 = *(const s8v*)(Alp2 + (OFF));                                                \
    Bv = *(const s8v*)(Bhp  + (OFF));                                                \
    Cv = *(const s8v*)(Blp  + (OFF));

#define WRITESET(A, A2, L, L2, Bv, Cv, BUF)                                          \
    *(s8v*)&Ash[BUF][wo]  = A;                                                       \
    *(s8v*)&Ash[BUF][wo2] = A2;                                                      \
    *(s8v*)&Asl[BUF][wo]  = L;                                                       \
    *(s8v*)&Asl[BUF][wo2] = L2;                                                      \
    *(s8v*)&Bsh[BUF][wo]  = Bv;                                                      \
    *(s8v*)&Bsl[BUF][wo]  = Cv;

#define GEMM_PREAMBLE(Kc)                                                            \
    int tid = threadIdx.x;                                                           \
    int m0 = blockIdx.y * 128, n0 = blockIdx.x * 64;                                 \
    int srow = tid >> 2, sg = tid & 3;                                               \
    int lane = tid & 63, wv = tid >> 6;                                              \
    int wm = (wv & 1) * 64, wn = (wv >> 1) * 32;                                     \
    int quad = lane >> 4, l15 = lane & 15;                                           \
    int wo = srow * PADK + sg * 8;                                                   \
    int wo2 = (srow + 64) * PADK + sg * 8;                                           \
    f4v acc[4][2];                                                                   \
    _Pragma("unroll")                                                                \
    for (int i = 0; i < 4; ++i)                                                      \
        _Pragma("unroll")                                                            \
        for (int j = 0; j < 2; ++j) acc[i][j] = (f4v){0.f, 0.f, 0.f, 0.f};           \
    const ushortt* Ahp  = Ahi + (size_t)(m0 + srow) * (Kc) + sg * 8;                 \
    const ushortt* Ahp2 = Ahp + (size_t)64 * (Kc);                                   \
    const ushortt* Alp  = Alo + (size_t)(m0 + srow) * (Kc) + sg * 8;                 \
    const ushortt* Alp2 = Alp + (size_t)64 * (Kc);                                   \
    const ushortt* Bhp  = Bh  + (size_t)(n0 + srow) * (Kc) + sg * 8;                 \
    const ushortt* Blp  = Bl  + (size_t)(n0 + srow) * (Kc) + sg * 8;

#define GEMM_MAIN(NT)                                                                \
    s8v a0, a0b, l0, l0b, b0, c0, a1, a1b, l1, l1b, b1, c1;                          \
    LOADSET(a0, a0b, l0, l0b, b0, c0, 0)                                             \
    WRITESET(a0, a0b, l0, l0b, b0, c0, 0)                                            \
    LOADSET(a1, a1b, l1, l1b, b1, c1, 32)                                            \
    __syncthreads();                                                                 \
    for (int k = 0; k < (NT); k += 2) {                                              \
        if (k + 2 < (NT)) { LOADSET(a0, a0b, l0, l0b, b0, c0, (k + 2) * 32) }        \
        GEMM_STEP(0)                                                                 \
        WRITESET(a1, a1b, l1, l1b, b1, c1, 1)                                        \
        __syncthreads();                                                             \
        if (k + 3 < (NT)) { LOADSET(a1, a1b, l1, l1b, b1, c1, (k + 3) * 32) }        \
        GEMM_STEP(1)                                                                 \
        if (k + 2 < (NT)) { WRITESET(a0, a0b, l0, l0b, b0, c0, 0) }                  \
        __syncthreads();                                                             \
    }

// ------------- GEMM1 (MFMA): [1344][1024] = A1 x Wconv^T + bconv, out hi/lo bf16 ---
// 128x64 tiles -> grid 16x11 = 176 blocks (single round on 256 CUs). Rows >= MTOT:
// loads read harmless workspace garbage (MFMA rows independent), stores guarded.
__global__ __launch_bounds__(256) void k_gemm1m(const ushortt* __restrict__ Ahi,
                                                const ushortt* __restrict__ Alo,
                                                const ushortt* __restrict__ Bh,
                                                const ushortt* __restrict__ Bl,
                                                const float* __restrict__ bias,
                                                ushortt* __restrict__ Chi,
                                                ushortt* __restrict__ Clo)
{
    const int K = CIN, N = CMID;
    __shared__ __align__(16) ushortt Ash[2][128 * PADK], Asl[2][128 * PADK];
    __shared__ __align__(16) ushortt Bsh[2][64 * PADK],  Bsl[2][64 * PADK];
    GEMM_PREAMBLE(K)
    GEMM_MAIN(K / 32)
#pragma unroll
    for (int sm = 0; sm < 4; ++sm)
#pragma unroll
        for (int sn = 0; sn < 2; ++sn)
#pragma unroll
            for (int r = 0; r < 4; ++r) {
                int m = m0 + wm + sm * 16 + quad * 4 + r;
                int n = n0 + wn + sn * 16 + l15;
                if (m < MTOT) {
                    float v = acc[sm][sn][r] + bias[n];
                    ushortt h = f2bf(v);
                    Chi[(size_t)m * N + n] = h;
                    Clo[(size_t)m * N + n] = f2bf(v - bf2f(h));
                }
            }
}

// ------------- GEMM2 (MFMA): C2[1344][1280] = A2 x B2pad^T + bias, fp32 out ---
// 128x64 tiles -> grid 20x11 = 220 blocks (single round).
__global__ __launch_bounds__(256) void k_gemm2m(const ushortt* __restrict__ Ahi,
                                                const ushortt* __restrict__ Alo,
                                                const ushortt* __restrict__ Bh,
                                                const ushortt* __restrict__ Bl,
                                                const float* __restrict__ bcls,
                                                const float* __restrict__ breg,
                                                float* __restrict__ C)
{
    const int K = CMID;
    __shared__ __align__(16) ushortt Ash[2][128 * PADK], Asl[2][128 * PADK];
    __shared__ __align__(16) ushortt Bsh[2][64 * PADK],  Bsl[2][64 * PADK];
    GEMM_PREAMBLE(K)
    GEMM_MAIN(K / 32)
#pragma unroll
    for (int sm = 0; sm < 4; ++sm)
#pragma unroll
        for (int sn = 0; sn < 2; ++sn)
#pragma unroll
            for (int r = 0; r < 4; ++r) {
                int m = m0 + wm + sm * 16 + quad * 4 + r;
                int n = n0 + wn + sn * 16 + l15;
                if (m < MTOT) {
                    float bb = (n < NCLS) ? bcls[n] : ((n < NCLS + NREGR) ? breg[n - NCLS] : 0.f);
                    C[(size_t)m * N2PAD + n] = acc[sm][sn][r] + bb;
                }
            }
}

// ---------------- assemble proposals + scores + start/end + xsel ----------------
__global__ __launch_bounds__(256) void k_assemble(const float* __restrict__ C2,
                                                  const float* __restrict__ AD,
                                                  float* __restrict__ outP,
                                                  float* __restrict__ outS,
                                                  float* __restrict__ startv,
                                                  float* __restrict__ endv,
                                                  float* __restrict__ xsel)
{
    int mb = blockIdx.x;                 // 0..1343
    int b = mb / NEDGE, e = mb - b * NEDGE;
    const float* c2 = C2 + (size_t)mb * N2PAD;
    int tid = threadIdx.x;
    for (int idx = tid; idx < NANG * NPREDD; idx += 256) {
        int a = idx / NPREDD, p = idx - a * NPREDD;
        int prop = e * NANG + a;
        float v;
        if (p < 2) v = c2[a * 2 + p];
        else {
            v = AD[prop * NPREDD + p];
            if (p >= 4) v += c2[NCLS + a * 73 + (p - 4)];
        }
        outP[((size_t)b * NPROPP + prop) * NPREDD + p] = v;
    }
    if (tid < NANG) {
        int a = tid, prop = e * NANG + a;
        float c0 = c2[2 * a], c1 = c2[2 * a + 1];
        float mx = fmaxf(c0, c1);
        float e0 = expf(c0 - mx), e1 = expf(c1 - mx);
        outS[b * NPROPP + prop] = e1 / (e0 + e1);
        float p2 = AD[prop * NPREDD + 2];
        float p4 = AD[prop * NPREDD + 4] + c2[NCLS + a * 73];
        float st = fminf(fmaxf(rintf(p2 * NSTRIPSF), 0.0f), NSTRIPSF);  // round half-to-even
        float en = fminf(fmaxf(st + p4 - 1.0f, 0.0f), NSTRIPSF);
        startv[b * 720 + prop] = st;
        endv[b * 720 + prop] = en;
        int ksi = (int)st;
        // bit-identical to outP[..][5+ksi]
        xsel[b * 720 + prop] = AD[prop * NPREDD + 5 + ksi] + c2[NCLS + a * 73 + ksi + 1];
    }
}

// ---------------- per-batch stable descending rank sort (parallel tiles) -------
__global__ __launch_bounds__(128) void k_sort(const float* __restrict__ scores,
                                              int* __restrict__ order)
{
    int b = blockIdx.x, tile = blockIdx.y, tid = threadIdx.x;
    __shared__ __align__(16) float s[720];
    for (int x = tid; x < 720; x += 128)
        s[x] = (x < NPROPP) ? scores[b * NPROPP + x] : -1e30f;
    __syncthreads();
    int i = tile * 128 + tid;
    if (i >= NPROPP) return;
    float si = s[i];
    int r = 0;
#pragma unroll 4
    for (int j4 = 0; j4 < 720; j4 += 4) {
        float4 v = *(const float4*)&s[j4];
        r += (v.x > si) || (v.x == si && (j4 + 0) < i);
        r += (v.y > si) || (v.y == si && (j4 + 1) < i);
        r += (v.z > si) || (v.z == si && (j4 + 2) < i);
        r += (v.w > si) || (v.w == si && (j4 + 3) < i);
    }
    order[b * 720 + r] = i;
}

// ---------------- suppression matrix, upper-triangle 64x64 tiles only ----------------
// grid (78, NB): blockIdx.x = triangular tile index over (it,jt), jt >= it.
// Below-diagonal words are never written; k_scan synthesizes them as 0.
__global__ __launch_bounds__(256) void k_supmat(const float* __restrict__ outP,
                                                const float* __restrict__ startv,
                                                const float* __restrict__ endv,
                                                const float* __restrict__ xsel,
                                                const int* __restrict__ order,
                                                u64* __restrict__ sup)
{
    int u = blockIdx.x, b = blockIdx.y;
    int it = 0, rem = 12;
    while (u >= rem) { u -= rem; --rem; ++it; }     // row it has 12-it tiles
    int jt = it + u;
    int i0 = it * 64, j0 = jt * 64;
    int tid = threadIdx.x;
    __shared__ float SI[64], EI[64], XI[64];
    __shared__ float SJ[64], EJ[64], XJ[64];
    __shared__ int   OI[64], OJ[64];
    if (tid < 128) {
        int side = tid >> 6, q = tid & 63;
        int pos = (side ? j0 : i0) + q;
        int o = (pos < NPROPP) ? order[b * 720 + pos] : -1;
        float st = (o >= 0) ? startv[b * 720 + o] : 0.f;
        float en = (o >= 0) ? endv[b * 720 + o] : -2.f;   // cnt<=-1 -> never suppress
        float xv = (o >= 0) ? xsel[b * 720 + o] : 0.f;
        if (!side) { SI[q] = st; EI[q] = en; XI[q] = xv; OI[q] = o; }
        else       { SJ[q] = st; EJ[q] = en; XJ[q] = xv; OJ[q] = o; }
    }
    __syncthreads();
    int lane = tid & 63, w = tid >> 6;
    int j = j0 + lane;
    float sj = SJ[lane], ej = EJ[lane], xj = XJ[lane];
    const float* basexs = outP + (size_t)b * NPROPP * NPREDD + 5;
#pragma unroll 1
    for (int rep = 0; rep < 16; ++rep) {
        int iloc = w * 16 + rep;
        int il = i0 + iloc;
        float si = SI[iloc], ei = EI[iloc];
        float s = fmaxf(si, sj), e = fminf(ei, ej);
        float cnt = e - s + 1.0f;
        bool sp = false;
        if (cnt > 0.f) {
            if (e < s) {
                sp = true;                               // empty range: dist = 0
            } else {
                int ks = (int)s, ke = (int)e;
                if (si == sj && ke == ks) {
                    sp = (fabsf(XI[iloc] - xj) / fmaxf(cnt, 1.0f)) < 15.0f;
                } else {                                  // rare general case
                    const float* xi  = basexs + (size_t)OI[iloc] * NPREDD;
                    const float* xjp = basexs + (size_t)OJ[lane] * NPREDD;
                    float sum = 0.f;
                    for (int k = ks; k <= ke; ++k)
                        sum += fabsf(xi[k] - xjp[k]);
                    sp = (sum / fmaxf(cnt, 1.0f)) < 15.0f;
                }
            }
        }
        bool valid = (il < NPROPP) && (j < NPROPP) && (j > il);
        u64 msk = __ballot(valid && sp);
        if (lane == 0 && il < NPROPP)
            sup[((size_t)b * NPROPP + il) * 12 + jt] = msk;
    }
}

// ---------------- NMS via Jacobi fixpoint (per batch, 256 threads) ----------------
// Greedy NMS keep is the UNIQUE fixpoint of keep[i] = !exists j<i: keep[j]&sup[j][i].
// Per sweep, the OR of kept rows is reduced wave-adaptively: when few lanes are
// active (late sweeps), direct predicated LDS atomicOr of nonzero words only;
// dense sweeps use the 64-lane butterfly. OR is commutative -> bit-identical.
__global__ __launch_bounds__(256) void k_scan(const u64* __restrict__ sup,
                                              const int* __restrict__ order,
                                              float* __restrict__ keep_out)
{
    int b = blockIdx.x, tid = threadIdx.x;
    int lane = tid & 63;
    __shared__ u64 K[12], NS[12];
    __shared__ int changed;
    const u64* base = sup + (size_t)b * NPROPP * 12;

    int r0 = tid, r1 = tid + 256, r2 = tid + 512;
    int t0 = r0 >> 6, t1 = r1 >> 6, t2 = r2 >> 6;   // first nonzero word per row
    u64 row0[12], row1[12], row2[12];
#pragma unroll
    for (int t = 0; t < 12; ++t) {
        row0[t] = (t >= t0) ? base[(size_t)r0 * 12 + t] : 0ull;    // r0 < 714 always
        row1[t] = (r1 < NPROPP && t >= t1) ? base[(size_t)r1 * 12 + t] : 0ull;
        row2[t] = (r2 < NPROPP && t >= t2) ? base[(size_t)r2 * 12 + t] : 0ull;
    }
    if (tid < 12) {
        K[tid] = (tid < 11) ? ~0ull : ((1ull << (NPROPP - 704)) - 1ull);  // valid mask
        NS[tid] = 0ull;
    }
    __syncthreads();

    for (int sweep = 0; sweep < 720; ++sweep) {
        u64 m0 = 0ull - ((K[r0 >> 6] >> (r0 & 63)) & 1ull);
        u64 m1 = (r1 < NPROPP) ? (0ull - ((K[r1 >> 6] >> (r1 & 63)) & 1ull)) : 0ull;
        u64 m2 = (r2 < NPROPP) ? (0ull - ((K[r2 >> 6] >> (r2 & 63)) & 1ull)) : 0ull;
        u64 a[12], any = 0ull;
#pragma unroll
        for (int t = 0; t < 12; ++t) {
            a[t] = (row0[t] & m0) | (row1[t] & m1) | (row2[t] & m2);
            any |= a[t];
        }
        if (tid == 0) changed = 0;
        u64 act = __ballot(any != 0ull);
        if (act) {
            if (__popcll(act) > 24) {                 // dense sweep: butterfly reduce
                unsigned lo[12], hi[12];
#pragma unroll
                for (int t = 0; t < 12; ++t) {
                    lo[t] = (unsigned)a[t];
                    hi[t] = (unsigned)(a[t] >> 32);
                }
#pragma unroll
                for (int s = 1; s < 64; s <<= 1) {
#pragma unroll
                    for (int t = 0; t < 12; ++t) {
                        lo[t] |= __shfl_xor(lo[t], s, 64);
                        hi[t] |= __shfl_xor(hi[t], s, 64);
                    }
                }
                if (lane == 0) {
#pragma unroll
                    for (int t = 0; t < 12; ++t) {
                        u64 w = ((u64)hi[t] << 32) | (u64)lo[t];
                        if (w) atomicOr(&NS[t], w);
                    }
                }
            } else if (any) {                          // sparse sweep: direct atomics
#pragma unroll
                for (int t = 0; t < 12; ++t)
                    if (a[t]) atomicOr(&NS[t], a[t]);
            }
        }
        __syncthreads();
        if (tid < 12) {
            u64 valid = (tid < 11) ? ~0ull : ((1ull << (NPROPP - 704)) - 1ull);
            u64 nk = valid & ~NS[tid];
            if (nk != K[tid]) changed = 1;   // benign race: same value
            K[tid] = nk;
            NS[tid] = 0ull;
        }
        __syncthreads();
        if (!changed) break;
    }
    if (r0 < NPROPP)
        keep_out[b * NPROPP + order[b * 720 + r0]] =
            ((K[r0 >> 6] >> (r0 & 63)) & 1ull) ? 1.f : 0.f;
    if (r1 < NPROPP)
        keep_out[b * NPROPP + order[b * 720 + r1]] =
            ((K[r1 >> 6] >> (r1 & 63)) & 1ull) ? 1.f : 0.f;
    if (r2 < NPROPP)
        keep_out[b * NPROPP + order[b * 720 + r2]] =
            ((K[r2 >> 6] >> (r2 & 63)) & 1ull) ? 1.f : 0.f;
}

extern "C" void kernel_launch(void* const* d_in, const int* in_sizes, int n_in,
                              void* d_out, int out_size, void* d_ws, size_t ws_size,
                              hipStream_t stream)
{
    const float* feat  = (const float*)d_in[0];
    const float* Wconv = (const float*)d_in[1];
    const float* bconv = (const float*)d_in[2];
    const float* Wcls  = (const float*)d_in[3];
    const float* bcls  = (const float*)d_in[4];
    const float* Wreg  = (const float*)d_in[5];
    const float* breg  = (const float*)d_in[6];
    const float* AD    = (const float*)d_in[8];   // anchors_anchor_dim (714,77)

    float* out  = (float*)d_out;
    float* outP = out;                                     // proposals 32*714*77
    float* outK = out + (size_t)NB * NPROPP * NPREDD;      // keep mask  32*714
    float* outS = outK + (size_t)NB * NPROPP;              // scores     32*714

    float* ws = (float*)d_ws;
    // [0, 688128) floats: A1hi/A1lo bf16 (dead after gemm1) -> NMS scratch later
    ushortt* A1hi = (ushortt*)ws;                          // 688128 bf16
    ushortt* A1lo = (ushortt*)(ws + 344064);               // 688128 bf16
    ushortt* A2hi = (ushortt*)(ws + 688128);               // 1344*1024 bf16
    ushortt* A2lo = (ushortt*)(ws + 1376256);              // 1344*1024 bf16
    float*   C2   = ws + 2064384;                          // 1344*1280 fp32, ends 3784704
    // preconverted weights (live through gemms, past C2):
    ushortt* B1h  = (ushortt*)(ws + 3784704);              // 1024*512 bf16
    ushortt* B1l  = (ushortt*)(ws + 4046848);
    ushortt* B2h  = (ushortt*)(ws + 4308992);              // 1280*1024 bf16
    ushortt* B2l  = (ushortt*)(ws + 4964352);              // ends @5619712 floats
    // NMS scratch overlays dead A1 region:
    float* startv = ws;                                    // 32*720 floats
    float* endv   = ws + 23040;                            // 32*720 floats
    int*   order  = (int*)(ws + 46080);                    // 32*720 ints
    u64*   sup    = (u64*)(ws + 69120);                    // 32*714*12 u64, ends @617472
    float* xsel   = ws + 617472;                           // 32*720 floats, ends @640512

    k_prep        <<<dim3(2304),       dim3(256), 0, stream>>>(feat, A1hi, A1lo,
                                                               Wconv, B1h, B1l,
                                                               Wcls, Wreg, B2h, B2l);
    k_gemm1m      <<<dim3(16, 11),     dim3(256), 0, stream>>>(A1hi, A1lo, B1h, B1l, bconv, A2hi, A2lo);
    k_gemm2m      <<<dim3(20, 11),     dim3(256), 0, stream>>>(A2hi, A2lo, B2h, B2l, bcls, breg, C2);
    k_assemble    <<<dim3(MTOT),       dim3(256), 0, stream>>>(C2, AD, outP, outS, startv, endv, xsel);
    k_sort        <<<dim3(NB, 6),      dim3(128), 0, stream>>>(outS, order);
    k_supmat      <<<dim3(78, NB),     dim3(256), 0, stream>>>(outP, startv, endv, xsel, order, sup);
    k_scan        <<<dim3(NB),         dim3(256), 0, stream>>>(sup, order, outK);
}

// Round 7
// 183.088 us; speedup vs baseline: 1.0440x; 1.0440x over previous
//
#include <hip/hip_runtime.h>
#include <math.h>

#define NB     32
#define FH     11
#define FW     20
#define CIN    512
#define CMID   1024
#define NANG   17
#define NPREDD 77
#define NEDGE  42
#define NPROPP 714
#define NOFF   72
#define NCLS   34
#define NREGR  1241
#define N2PAD  1280
#define MTOT   1344      // NB * NEDGE
#define NSTRIPSF 71.0f
#define PADK   40        // padded LDS row length in bf16 units (2-way-only b128 reads)

typedef unsigned long long u64;
typedef unsigned short ushortt;
typedef short s8v __attribute__((ext_vector_type(8)));
typedef ushortt u4v __attribute__((ext_vector_type(4)));
typedef float f4v __attribute__((ext_vector_type(4)));

__device__ inline ushortt f2bf(float f) {          // RNE fp32 -> bf16
    unsigned u = __float_as_uint(f);
    u += 0x7fffu + ((u >> 16) & 1u);
    return (ushortt)(u >> 16);
}
__device__ inline float bf2f(ushortt h) {
    return __uint_as_float(((unsigned)h) << 16);
}

// ------------- prep: coalesced LDS-transpose gather + pre-split ALL weights hi/lo ---
__global__ __launch_bounds__(256) void k_prep(const float* __restrict__ feat,
                                              ushortt* __restrict__ A1hi,
                                              ushortt* __restrict__ A1lo,
                                              const float* __restrict__ Wconv,
                                              ushortt* __restrict__ B1h,
                                              ushortt* __restrict__ B1l,
                                              const float* __restrict__ Wcls,
                                              const float* __restrict__ Wreg,
                                              ushortt* __restrict__ B2h,
                                              ushortt* __restrict__ B2l)
{
    __shared__ unsigned T[32 * 221];               // packed (hi|lo<<16), row pad 221 (conflict-free)
    int bid = blockIdx.x, tid = threadIdx.x;
    if (bid < 512) {
        int p0 = bid * 32;                         // first (b,c) plane, 32 planes/block, same b
        int b  = p0 >> 9;
        int c0 = p0 & 511;
        const float* fp = feat + (size_t)p0 * 220;
        for (int i = tid; i < 32 * 220; i += 256) {      // fully coalesced read of 32 planes
            float v = fp[i];
            int pl = i / 220, off = i - pl * 220;
            ushortt hi = f2bf(v);
            ushortt lo = f2bf(v - bf2f(hi));
            T[pl * 221 + off] = ((unsigned)hi) | (((unsigned)lo) << 16);
        }
        __syncthreads();
        int cl = tid & 31;
        for (int e = tid >> 5; e < NEDGE; e += 8) {      // 64B-burst writes into A1
            int hw = (e < FH) ? e * FW
                   : (e < 2 * FH) ? (e - FH) * FW + (FW - 1)
                   : (FH - 1) * FW + (e - 2 * FH);
            unsigned u = T[cl * 221 + hw];
            size_t o = (size_t)(b * NEDGE + e) * CIN + c0 + cl;
            A1hi[o] = (ushortt)(u & 0xffffu);
            A1lo[o] = (ushortt)(u >> 16);
        }
    } else if (bid < 1024) {
        int t = (bid - 512) * 256 + tid;           // 131072 threads x 4 elems
        float4 v = *(const float4*)(Wconv + (size_t)t * 4);
        float vf[4] = {v.x, v.y, v.z, v.w};
        u4v hv, lv;
#pragma unroll
        for (int j = 0; j < 4; ++j) {
            ushortt h = f2bf(vf[j]);
            hv[j] = h;
            lv[j] = f2bf(vf[j] - bf2f(h));
        }
        *(u4v*)(B1h + (size_t)t * 4) = hv;
        *(u4v*)(B1l + (size_t)t * 4) = lv;
    } else {
        int t = (bid - 1024) * 256 + tid;          // 327680 threads x 4 elems
        int row = t >> 8, col = (t & 255) * 4;
        float4 v = make_float4(0.f, 0.f, 0.f, 0.f);
        if (row < NCLS)              v = *(const float4*)(Wcls + (size_t)row * CMID + col);
        else if (row < NCLS + NREGR) v = *(const float4*)(Wreg + (size_t)(row - NCLS) * CMID + col);
        float vf[4] = {v.x, v.y, v.z, v.w};
        u4v hv, lv;
#pragma unroll
        for (int j = 0; j < 4; ++j) {
            ushortt h = f2bf(vf[j]);
            hv[j] = h;
            lv[j] = f2bf(vf[j] - bf2f(h));
        }
        *(u4v*)(B2h + (size_t)t * 4) = hv;
        *(u4v*)(B2l + (size_t)t * 4) = lv;
    }
}

// ===== 64x64-tile MFMA GEMM (4 blocks/CU: the measured-best occupancy point) =====
// one k-step: ds_read fragments from LDS buffer BUF + 16 MFMA (4-product hi/lo emu)
#define GEMM_STEP(BUF)                                                               \
    {                                                                                \
        s8v ah[2], al[2], bh[2], bl[2];                                              \
        _Pragma("unroll")                                                            \
        for (int s = 0; s < 2; ++s) {                                                \
            ah[s] = *(const s8v*)&Ash[BUF][(wm + s * 16 + l15) * PADK + quad * 8];   \
            al[s] = *(const s8v*)&Asl[BUF][(wm + s * 16 + l15) * PADK + quad * 8];   \
            bh[s] = *(const s8v*)&Bsh[BUF][(wn + s * 16 + l15) * PADK + quad * 8];   \
            bl[s] = *(const s8v*)&Bsl[BUF][(wn + s * 16 + l15) * PADK + quad * 8];   \
        }                                                                            \
        _Pragma("unroll")                                                            \
        for (int sm = 0; sm < 2; ++sm)                                               \
            _Pragma("unroll")                                                        \
            for (int sn = 0; sn < 2; ++sn) {                                         \
                acc[sm][sn] = __builtin_amdgcn_mfma_f32_16x16x32_bf16(al[sm], bl[sn], acc[sm][sn], 0, 0, 0); \
                acc[sm][sn] = __builtin_amdgcn_mfma_f32_16x16x32_bf16(al[sm], bh[sn], acc[sm][sn], 0, 0, 0); \
                acc[sm][sn] = __builtin_amdgcn_mfma_f32_16x16x32_bf16(ah[sm], bl[sn], acc[sm][sn], 0, 0, 0); \
                acc[sm][sn] = __builtin_amdgcn_mfma_f32_16x16x32_bf16(ah[sm], bh[sn], acc[sm][sn], 0, 0, 0); \
            }                                                                        \
    }

#define LOADSET(dst_a, dst_l, dst_b, dst_c, OFF)                                     \
    dst_a = *(const s8v*)(Ahp + (OFF));                                              \
    dst_l = *(const s8v*)(Alp + (OFF));                                              \
    dst_b = *(const s8v*)(Bhp + (OFF));                                              \
    dst_c = *(const s8v*)(Blp + (OFF));

#define WRITESET(src_a, src_l, src_b, src_c, BUF)                                    \
    *(s8v*)&Ash[BUF][wo] = src_a;                                                    \
    *(s8v*)&Asl[BUF][wo] = src_l;                                                    \
    *(s8v*)&Bsh[BUF][wo] = src_b;                                                    \
    *(s8v*)&Bsl[BUF][wo] = src_c;

// ------------- GEMM1 (MFMA): [1344][1024] = A1 x Wconv^T + bconv, out hi/lo bf16 ---
// Preconverted B, 2-deep register prefetch (2 iters of latency cover), 1 barrier/k-step.
__global__ __launch_bounds__(256) void k_gemm1m(const ushortt* __restrict__ Ahi,
                                                const ushortt* __restrict__ Alo,
                                                const ushortt* __restrict__ Bh,
                                                const ushortt* __restrict__ Bl,
                                                const float* __restrict__ bias,
                                                ushortt* __restrict__ Chi,
                                                ushortt* __restrict__ Clo)
{
    const int K = CIN, N = CMID;
    const int NT = K / 32;                          // 16 (even)
    __shared__ __align__(16) ushortt Ash[2][64 * PADK], Asl[2][64 * PADK];
    __shared__ __align__(16) ushortt Bsh[2][64 * PADK], Bsl[2][64 * PADK];
    int tid = threadIdx.x;
    int m0 = blockIdx.y * 64, n0 = blockIdx.x * 64;
    int srow = tid >> 2, sg = tid & 3;
    int lane = tid & 63, wv = tid >> 6;
    int wm = (wv & 1) * 32, wn = (wv >> 1) * 32;
    int quad = lane >> 4, l15 = lane & 15;
    int wo = srow * PADK + sg * 8;

    f4v acc[2][2];
#pragma unroll
    for (int i = 0; i < 2; ++i)
#pragma unroll
        for (int j = 0; j < 2; ++j) acc[i][j] = (f4v){0.f, 0.f, 0.f, 0.f};

    const ushortt* Ahp = Ahi + (size_t)(m0 + srow) * K + sg * 8;
    const ushortt* Alp = Alo + (size_t)(m0 + srow) * K + sg * 8;
    const ushortt* Bhp = Bh  + (size_t)(n0 + srow) * K + sg * 8;
    const ushortt* Blp = Bl  + (size_t)(n0 + srow) * K + sg * 8;

    // prologue: tile0 -> set0 -> LDS[0]; tile1 -> set1 (held in regs)
    s8v a0, l0, b0, c0, a1, l1, b1, c1;
    LOADSET(a0, l0, b0, c0, 0)
    WRITESET(a0, l0, b0, c0, 0)
    LOADSET(a1, l1, b1, c1, 32)
    __syncthreads();

    for (int k = 0; k < NT; k += 2) {
        // even sub-iter: compute tile k (LDS[0]); prefetch tile k+2 -> set0; write tile k+1 -> LDS[1]
        if (k + 2 < NT) { LOADSET(a0, l0, b0, c0, (k + 2) * 32) }
        GEMM_STEP(0)
        WRITESET(a1, l1, b1, c1, 1)                 // tile k+1 (k+1 <= NT-1 always)
        __syncthreads();
        // odd sub-iter: compute tile k+1 (LDS[1]); prefetch tile k+3 -> set1; write tile k+2 -> LDS[0]
        if (k + 3 < NT) { LOADSET(a1, l1, b1, c1, (k + 3) * 32) }
        GEMM_STEP(1)
        if (k + 2 < NT) { WRITESET(a0, l0, b0, c0, 0) }
        __syncthreads();
    }
#pragma unroll
    for (int sm = 0; sm < 2; ++sm)
#pragma unroll
        for (int sn = 0; sn < 2; ++sn)
#pragma unroll
            for (int r = 0; r < 4; ++r) {
                int m = m0 + wm + sm * 16 + quad * 4 + r;
                int n = n0 + wn + sn * 16 + l15;
                float v = acc[sm][sn][r] + bias[n];
                ushortt h = f2bf(v);
                Chi[(size_t)m * N + n] = h;
                Clo[(size_t)m * N + n] = f2bf(v - bf2f(h));
            }
}

// ------------- GEMM2 (MFMA): C2[1344][1280] = A2 x B2pad^T + bias, fp32 out ---
__global__ __launch_bounds__(256) void k_gemm2m(const ushortt* __restrict__ Ahi,
                                                const ushortt* __restrict__ Alo,
                                                const ushortt* __restrict__ Bh,
                                                const ushortt* __restrict__ Bl,
                                                const float* __restrict__ bcls,
                                                const float* __restrict__ breg,
                                                float* __restrict__ C)
{
    const int K = CMID;
    const int NT = K / 32;                          // 32 (even)
    __shared__ __align__(16) ushortt Ash[2][64 * PADK], Asl[2][64 * PADK];
    __shared__ __align__(16) ushortt Bsh[2][64 * PADK], Bsl[2][64 * PADK];
    int tid = threadIdx.x;
    int m0 = blockIdx.y * 64, n0 = blockIdx.x * 64;
    int srow = tid >> 2, sg = tid & 3;
    int lane = tid & 63, wv = tid >> 6;
    int wm = (wv & 1) * 32, wn = (wv >> 1) * 32;
    int quad = lane >> 4, l15 = lane & 15;
    int wo = srow * PADK + sg * 8;

    f4v acc[2][2];
#pragma unroll
    for (int i = 0; i < 2; ++i)
#pragma unroll
        for (int j = 0; j < 2; ++j) acc[i][j] = (f4v){0.f, 0.f, 0.f, 0.f};

    const ushortt* Ahp = Ahi + (size_t)(m0 + srow) * K + sg * 8;
    const ushortt* Alp = Alo + (size_t)(m0 + srow) * K + sg * 8;
    const ushortt* Bhp = Bh  + (size_t)(n0 + srow) * K + sg * 8;
    const ushortt* Blp = Bl  + (size_t)(n0 + srow) * K + sg * 8;

    s8v a0, l0, b0, c0, a1, l1, b1, c1;
    LOADSET(a0, l0, b0, c0, 0)
    WRITESET(a0, l0, b0, c0, 0)
    LOADSET(a1, l1, b1, c1, 32)
    __syncthreads();

    for (int k = 0; k < NT; k += 2) {
        if (k + 2 < NT) { LOADSET(a0, l0, b0, c0, (k + 2) * 32) }
        GEMM_STEP(0)
        WRITESET(a1, l1, b1, c1, 1)
        __syncthreads();
        if (k + 3 < NT) { LOADSET(a1, l1, b1, c1, (k + 3) * 32) }
        GEMM_STEP(1)
        if (k + 2 < NT) { WRITESET(a0, l0, b0, c0, 0) }
        __syncthreads();
    }
#pragma unroll
    for (int sm = 0; sm < 2; ++sm)
#pragma unroll
        for (int sn = 0; sn < 2; ++sn)
#pragma unroll
            for (int r = 0; r < 4; ++r) {
                int m = m0 + wm + sm * 16 + quad * 4 + r;
                int n = n0 + wn + sn * 16 + l15;
                float bb = (n < NCLS) ? bcls[n] : ((n < NCLS + NREGR) ? breg[n - NCLS] : 0.f);
                C[(size_t)m * N2PAD + n] = acc[sm][sn][r] + bb;
            }
}

// ---------------- assemble proposals + scores + start/end + xsel ----------------
__global__ __launch_bounds__(256) void k_assemble(const float* __restrict__ C2,
                                                  const float* __restrict__ AD,
                                                  float* __restrict__ outP,
                                                  float* __restrict__ outS,
                                                  float* __restrict__ startv,
                                                  float* __restrict__ endv,
                                                  float* __restrict__ xsel)
{
    int mb = blockIdx.x;                 // 0..1343
    int b = mb / NEDGE, e = mb - b * NEDGE;
    const float* c2 = C2 + (size_t)mb * N2PAD;
    int tid = threadIdx.x;
    for (int idx = tid; idx < NANG * NPREDD; idx += 256) {
        int a = idx / NPREDD, p = idx - a * NPREDD;
        int prop = e * NANG + a;
        float v;
        if (p < 2) v = c2[a * 2 + p];
        else {
            v = AD[prop * NPREDD + p];
            if (p >= 4) v += c2[NCLS + a * 73 + (p - 4)];
        }
        outP[((size_t)b * NPROPP + prop) * NPREDD + p] = v;
    }
    if (tid < NANG) {
        int a = tid, prop = e * NANG + a;
        float c0 = c2[2 * a], c1 = c2[2 * a + 1];
        float mx = fmaxf(c0, c1);
        float e0 = expf(c0 - mx), e1 = expf(c1 - mx);
        outS[b * NPROPP + prop] = e1 / (e0 + e1);
        float p2 = AD[prop * NPREDD + 2];
        float p4 = AD[prop * NPREDD + 4] + c2[NCLS + a * 73];
        float st = fminf(fmaxf(rintf(p2 * NSTRIPSF), 0.0f), NSTRIPSF);  // round half-to-even
        float en = fminf(fmaxf(st + p4 - 1.0f, 0.0f), NSTRIPSF);
        startv[b * 720 + prop] = st;
        endv[b * 720 + prop] = en;
        int ksi = (int)st;
        // bit-identical to outP[..][5+ksi]
        xsel[b * 720 + prop] = AD[prop * NPREDD + 5 + ksi] + c2[NCLS + a * 73 + ksi + 1];
    }
}

// ---------------- per-batch stable descending rank sort (parallel tiles) -------
__global__ __launch_bounds__(128) void k_sort(const float* __restrict__ scores,
                                              int* __restrict__ order)
{
    int b = blockIdx.x, tile = blockIdx.y, tid = threadIdx.x;
    __shared__ __align__(16) float s[720];
    for (int x = tid; x < 720; x += 128)
        s[x] = (x < NPROPP) ? scores[b * NPROPP + x] : -1e30f;
    __syncthreads();
    int i = tile * 128 + tid;
    if (i >= NPROPP) return;
    float si = s[i];
    int r = 0;
#pragma unroll 4
    for (int j4 = 0; j4 < 720; j4 += 4) {
        float4 v = *(const float4*)&s[j4];
        r += (v.x > si) || (v.x == si && (j4 + 0) < i);
        r += (v.y > si) || (v.y == si && (j4 + 1) < i);
        r += (v.z > si) || (v.z == si && (j4 + 2) < i);
        r += (v.w > si) || (v.w == si && (j4 + 3) < i);
    }
    order[b * 720 + r] = i;
}

// ---------------- suppression matrix, upper-triangle 64x64 tiles only ----------------
// grid (78, NB): blockIdx.x = triangular tile index over (it,jt), jt >= it.
// Below-diagonal words are never written; k_scan synthesizes them as 0.
__global__ __launch_bounds__(256) void k_supmat(const float* __restrict__ outP,
                                                const float* __restrict__ startv,
                                                const float* __restrict__ endv,
                                                const float* __restrict__ xsel,
                                                const int* __restrict__ order,
                                                u64* __restrict__ sup)
{
    int u = blockIdx.x, b = blockIdx.y;
    int it = 0, rem = 12;
    while (u >= rem) { u -= rem; --rem; ++it; }     // row it has 12-it tiles
    int jt = it + u;
    int i0 = it * 64, j0 = jt * 64;
    int tid = threadIdx.x;
    __shared__ float SI[64], EI[64], XI[64];
    __shared__ float SJ[64], EJ[64], XJ[64];
    __shared__ int   OI[64], OJ[64];
    if (tid < 128) {
        int side = tid >> 6, q = tid & 63;
        int pos = (side ? j0 : i0) + q;
        int o = (pos < NPROPP) ? order[b * 720 + pos] : -1;
        float st = (o >= 0) ? startv[b * 720 + o] : 0.f;
        float en = (o >= 0) ? endv[b * 720 + o] : -2.f;   // cnt<=-1 -> never suppress
        float xv = (o >= 0) ? xsel[b * 720 + o] : 0.f;
        if (!side) { SI[q] = st; EI[q] = en; XI[q] = xv; OI[q] = o; }
        else       { SJ[q] = st; EJ[q] = en; XJ[q] = xv; OJ[q] = o; }
    }
    __syncthreads();
    int lane = tid & 63, w = tid >> 6;
    int j = j0 + lane;
    float sj = SJ[lane], ej = EJ[lane], xj = XJ[lane];
    const float* basexs = outP + (size_t)b * NPROPP * NPREDD + 5;
#pragma unroll 1
    for (int rep = 0; rep < 16; ++rep) {
        int iloc = w * 16 + rep;
        int il = i0 + iloc;
        float si = SI[iloc], ei = EI[iloc];
        float s = fmaxf(si, sj), e = fminf(ei, ej);
        float cnt = e - s + 1.0f;
        bool sp = false;
        if (cnt > 0.f) {
            if (e < s) {
                sp = true;                               // empty range: dist = 0
            } else {
                int ks = (int)s, ke = (int)e;
                if (si == sj && ke == ks) {
                    sp = (fabsf(XI[iloc] - xj) / fmaxf(cnt, 1.0f)) < 15.0f;
                } else {                                  // rare general case
                    const float* xi  = basexs + (size_t)OI[iloc] * NPREDD;
                    const float* xjp = basexs + (size_t)OJ[lane] * NPREDD;
                    float sum = 0.f;
                    for (int k = ks; k <= ke; ++k)
                        sum += fabsf(xi[k] - xjp[k]);
                    sp = (sum / fmaxf(cnt, 1.0f)) < 15.0f;
                }
            }
        }
        bool valid = (il < NPROPP) && (j < NPROPP) && (j > il);
        u64 msk = __ballot(valid && sp);
        if (lane == 0 && il < NPROPP)
            sup[((size_t)b * NPROPP + il) * 12 + jt] = msk;
    }
}

// ---------------- NMS via Jacobi fixpoint (per batch, 256 threads) ----------------
// Greedy NMS keep is the UNIQUE fixpoint of keep[i] = !exists j<i: keep[j]&sup[j][i].
// Per sweep, the OR of kept rows is reduced wave-adaptively: when few lanes are
// active (late sweeps), direct predicated LDS atomicOr of nonzero words only;
// dense sweeps use the 64-lane butterfly. OR is commutative -> bit-identical.
__global__ __launch_bounds__(256) void k_scan(const u64* __restrict__ sup,
                                              const int* __restrict__ order,
                                              float* __restrict__ keep_out)
{
    int b = blockIdx.x, tid = threadIdx.x;
    int lane = tid & 63;
    __shared__ u64 K[12], NS[12];
    __shared__ int changed;
    const u64* base = sup + (size_t)b * NPROPP * 12;

    int r0 = tid, r1 = tid + 256, r2 = tid + 512;
    int t0 = r0 >> 6, t1 = r1 >> 6, t2 = r2 >> 6;   // first nonzero word per row
    u64 row0[12], row1[12], row2[12];
#pragma unroll
    for (int t = 0; t < 12; ++t) {
        row0[t] = (t >= t0) ? base[(size_t)r0 * 12 + t] : 0ull;    // r0 < 714 always
        row1[t] = (r1 < NPROPP && t >= t1) ? base[(size_t)r1 * 12 + t] : 0ull;
        row2[t] = (r2 < NPROPP && t >= t2) ? base[(size_t)r2 * 12 + t] : 0ull;
    }
    if (tid < 12) {
        K[tid] = (tid < 11) ? ~0ull : ((1ull << (NPROPP - 704)) - 1ull);  // valid mask
        NS[tid] = 0ull;
    }
    __syncthreads();

    for (int sweep = 0; sweep < 720; ++sweep) {
        u64 m0 = 0ull - ((K[r0 >> 6] >> (r0 & 63)) & 1ull);
        u64 m1 = (r1 < NPROPP) ? (0ull - ((K[r1 >> 6] >> (r1 & 63)) & 1ull)) : 0ull;
        u64 m2 = (r2 < NPROPP) ? (0ull - ((K[r2 >> 6] >> (r2 & 63)) & 1ull)) : 0ull;
        u64 a[12], any = 0ull;
#pragma unroll
        for (int t = 0; t < 12; ++t) {
            a[t] = (row0[t] & m0) | (row1[t] & m1) | (row2[t] & m2);
            any |= a[t];
        }
        if (tid == 0) changed = 0;
        u64 act = __ballot(any != 0ull);
        if (act) {
            if (__popcll(act) > 24) {                 // dense sweep: butterfly reduce
                unsigned lo[12], hi[12];
#pragma unroll
                for (int t = 0; t < 12; ++t) {
                    lo[t] = (unsigned)a[t];
                    hi[t] = (unsigned)(a[t] >> 32);
                }
#pragma unroll
                for (int s = 1; s < 64; s <<= 1) {
#pragma unroll
                    for (int t = 0; t < 12; ++t) {
                        lo[t] |= __shfl_xor(lo[t], s, 64);
                        hi[t] |= __shfl_xor(hi[t], s, 64);
                    }
                }
                if (lane == 0) {
#pragma unroll
                    for (int t = 0; t < 12; ++t) {
                        u64 w = ((u64)hi[t] << 32) | (u64)lo[t];
                        if (w) atomicOr(&NS[t], w);
                    }
                }
            } else if (any) {                          // sparse sweep: direct atomics
#pragma unroll
                for (int t = 0; t < 12; ++t)
                    if (a[t]) atomicOr(&NS[t], a[t]);
            }
        }
        __syncthreads();
        if (tid < 12) {
            u64 valid = (tid < 11) ? ~0ull : ((1ull << (NPROPP - 704)) - 1ull);
            u64 nk = valid & ~NS[tid];
            if (nk != K[tid]) changed = 1;   // benign race: same value
            K[tid] = nk;
            NS[tid] = 0ull;
        }
        __syncthreads();
        if (!changed) break;
    }
    if (r0 < NPROPP)
        keep_out[b * NPROPP + order[b * 720 + r0]] =
            ((K[r0 >> 6] >> (r0 & 63)) & 1ull) ? 1.f : 0.f;
    if (r1 < NPROPP)
        keep_out[b * NPROPP + order[b * 720 + r1]] =
            ((K[r1 >> 6] >> (r1 & 63)) & 1ull) ? 1.f : 0.f;
    if (r2 < NPROPP)
        keep_out[b * NPROPP + order[b * 720 + r2]] =
            ((K[r2 >> 6] >> (r2 & 63)) & 1ull) ? 1.f : 0.f;
}

extern "C" void kernel_launch(void* const* d_in, const int* in_sizes, int n_in,
                              void* d_out, int out_size, void* d_ws, size_t ws_size,
                              hipStream_t stream)
{
    const float* feat  = (const float*)d_in[0];
    const float* Wconv = (const float*)d_in[1];
    const float* bconv = (const float*)d_in[2];
    const float* Wcls  = (const float*)d_in[3];
    const float* bcls  = (const float*)d_in[4];
    const float* Wreg  = (const float*)d_in[5];
    const float* breg  = (const float*)d_in[6];
    const float* AD    = (const float*)d_in[8];   // anchors_anchor_dim (714,77)

    float* out  = (float*)d_out;
    float* outP = out;                                     // proposals 32*714*77
    float* outK = out + (size_t)NB * NPROPP * NPREDD;      // keep mask  32*714
    float* outS = outK + (size_t)NB * NPROPP;              // scores     32*714

    float* ws = (float*)d_ws;
    // [0, 688128) floats: A1hi/A1lo bf16 (dead after gemm1) -> NMS scratch later
    ushortt* A1hi = (ushortt*)ws;                          // 688128 bf16
    ushortt* A1lo = (ushortt*)(ws + 344064);               // 688128 bf16
    ushortt* A2hi = (ushortt*)(ws + 688128);               // 1344*1024 bf16
    ushortt* A2lo = (ushortt*)(ws + 1376256);              // 1344*1024 bf16
    float*   C2   = ws + 2064384;                          // 1344*1280 fp32, ends 3784704
    // preconverted weights (live through gemms, past C2):
    ushortt* B1h  = (ushortt*)(ws + 3784704);              // 1024*512 bf16
    ushortt* B1l  = (ushortt*)(ws + 4046848);
    ushortt* B2h  = (ushortt*)(ws + 4308992);              // 1280*1024 bf16
    ushortt* B2l  = (ushortt*)(ws + 4964352);              // ends @5619712 floats
    // NMS scratch overlays dead A1 region:
    float* startv = ws;                                    // 32*720 floats
    float* endv   = ws + 23040;                            // 32*720 floats
    int*   order  = (int*)(ws + 46080);                    // 32*720 ints
    u64*   sup    = (u64*)(ws + 69120);                    // 32*714*12 u64, ends @617472
    float* xsel   = ws + 617472;                           // 32*720 floats, ends @640512

    k_prep        <<<dim3(2304),       dim3(256), 0, stream>>>(feat, A1hi, A1lo,
                                                               Wconv, B1h, B1l,
                                                               Wcls, Wreg, B2h, B2l);
    k_gemm1m      <<<dim3(16, 21),     dim3(256), 0, stream>>>(A1hi, A1lo, B1h, B1l, bconv, A2hi, A2lo);
    k_gemm2m      <<<dim3(20, 21),     dim3(256), 0, stream>>>(A2hi, A2lo, B2h, B2l, bcls, breg, C2);
    k_assemble    <<<dim3(MTOT),       dim3(256), 0, stream>>>(C2, AD, outP, outS, startv, endv, xsel);
    k_sort        <<<dim3(NB, 6),      dim3(128), 0, stream>>>(outS, order);
    k_supmat      <<<dim3(78, NB),     dim3(256), 0, stream>>>(outP, startv, endv, xsel, order, sup);
    k_scan        <<<dim3(NB),         dim3(256), 0, stream>>>(sup, order, outK);
}

// Round 8
// 174.409 us; speedup vs baseline: 1.0960x; 1.0498x over previous
//
#include <hip/hip_runtime.h>
#include <math.h>

#define NB     32
#define FH     11
#define FW     20
#define CIN    512
#define CMID   1024
#define NANG   17
#define NPREDD 77
#define NEDGE  42
#define NPROPP 714
#define NOFF   72
#define NCLS   34
#define NREGR  1241
#define N2PAD  1280
#define MTOT   1344      // NB * NEDGE
#define NSTRIPSF 71.0f
#define PADK   40        // padded LDS row length in bf16 units (2-way-only b128 reads)

typedef unsigned long long u64;
typedef unsigned short ushortt;
typedef short s8v __attribute__((ext_vector_type(8)));
typedef ushortt u4v __attribute__((ext_vector_type(4)));
typedef float f4v __attribute__((ext_vector_type(4)));

__device__ inline ushortt f2bf(float f) {          // RNE fp32 -> bf16
    unsigned u = __float_as_uint(f);
    u += 0x7fffu + ((u >> 16) & 1u);
    return (ushortt)(u >> 16);
}
__device__ inline float bf2f(ushortt h) {
    return __uint_as_float(((unsigned)h) << 16);
}

// ------------- prep: coalesced LDS-transpose gather + pre-split ALL weights hi/lo ---
__global__ __launch_bounds__(256) void k_prep(const float* __restrict__ feat,
                                              ushortt* __restrict__ A1hi,
                                              ushortt* __restrict__ A1lo,
                                              const float* __restrict__ Wconv,
                                              ushortt* __restrict__ B1h,
                                              ushortt* __restrict__ B1l,
                                              const float* __restrict__ Wcls,
                                              const float* __restrict__ Wreg,
                                              ushortt* __restrict__ B2h,
                                              ushortt* __restrict__ B2l)
{
    __shared__ unsigned T[32 * 221];               // packed (hi|lo<<16), row pad 221 (conflict-free)
    int bid = blockIdx.x, tid = threadIdx.x;
    if (bid < 512) {
        int p0 = bid * 32;                         // first (b,c) plane, 32 planes/block, same b
        int b  = p0 >> 9;
        int c0 = p0 & 511;
        const float* fp = feat + (size_t)p0 * 220;
        for (int i = tid; i < 32 * 220; i += 256) {      // fully coalesced read of 32 planes
            float v = fp[i];
            int pl = i / 220, off = i - pl * 220;
            ushortt hi = f2bf(v);
            ushortt lo = f2bf(v - bf2f(hi));
            T[pl * 221 + off] = ((unsigned)hi) | (((unsigned)lo) << 16);
        }
        __syncthreads();
        int cl = tid & 31;
        for (int e = tid >> 5; e < NEDGE; e += 8) {      // 64B-burst writes into A1
            int hw = (e < FH) ? e * FW
                   : (e < 2 * FH) ? (e - FH) * FW + (FW - 1)
                   : (FH - 1) * FW + (e - 2 * FH);
            unsigned u = T[cl * 221 + hw];
            size_t o = (size_t)(b * NEDGE + e) * CIN + c0 + cl;
            A1hi[o] = (ushortt)(u & 0xffffu);
            A1lo[o] = (ushortt)(u >> 16);
        }
    } else if (bid < 1024) {
        int t = (bid - 512) * 256 + tid;           // 131072 threads x 4 elems
        float4 v = *(const float4*)(Wconv + (size_t)t * 4);
        float vf[4] = {v.x, v.y, v.z, v.w};
        u4v hv, lv;
#pragma unroll
        for (int j = 0; j < 4; ++j) {
            ushortt h = f2bf(vf[j]);
            hv[j] = h;
            lv[j] = f2bf(vf[j] - bf2f(h));
        }
        *(u4v*)(B1h + (size_t)t * 4) = hv;
        *(u4v*)(B1l + (size_t)t * 4) = lv;
    } else {
        int t = (bid - 1024) * 256 + tid;          // 327680 threads x 4 elems
        int row = t >> 8, col = (t & 255) * 4;
        float4 v = make_float4(0.f, 0.f, 0.f, 0.f);
        if (row < NCLS)              v = *(const float4*)(Wcls + (size_t)row * CMID + col);
        else if (row < NCLS + NREGR) v = *(const float4*)(Wreg + (size_t)(row - NCLS) * CMID + col);
        float vf[4] = {v.x, v.y, v.z, v.w};
        u4v hv, lv;
#pragma unroll
        for (int j = 0; j < 4; ++j) {
            ushortt h = f2bf(vf[j]);
            hv[j] = h;
            lv[j] = f2bf(vf[j] - bf2f(h));
        }
        *(u4v*)(B2h + (size_t)t * 4) = hv;
        *(u4v*)(B2l + (size_t)t * 4) = lv;
    }
}

// one k-step: ds_read fragments from LDS buffer BUF + 16 MFMA (4-product hi/lo emu)
#define GEMM_STEP(BUF)                                                               \
    {                                                                                \
        s8v ah[2], al[2], bh[2], bl[2];                                              \
        _Pragma("unroll")                                                            \
        for (int s = 0; s < 2; ++s) {                                                \
            ah[s] = *(const s8v*)&Ash[BUF][(wm + s * 16 + l15) * PADK + quad * 8];   \
            al[s] = *(const s8v*)&Asl[BUF][(wm + s * 16 + l15) * PADK + quad * 8];   \
            bh[s] = *(const s8v*)&Bsh[BUF][(wn + s * 16 + l15) * PADK + quad * 8];   \
            bl[s] = *(const s8v*)&Bsl[BUF][(wn + s * 16 + l15) * PADK + quad * 8];   \
        }                                                                            \
        _Pragma("unroll")                                                            \
        for (int sm = 0; sm < 2; ++sm)                                               \
            _Pragma("unroll")                                                        \
            for (int sn = 0; sn < 2; ++sn) {                                         \
                acc[sm][sn] = __builtin_amdgcn_mfma_f32_16x16x32_bf16(al[sm], bl[sn], acc[sm][sn], 0, 0, 0); \
                acc[sm][sn] = __builtin_amdgcn_mfma_f32_16x16x32_bf16(al[sm], bh[sn], acc[sm][sn], 0, 0, 0); \
                acc[sm][sn] = __builtin_amdgcn_mfma_f32_16x16x32_bf16(ah[sm], bl[sn], acc[sm][sn], 0, 0, 0); \
                acc[sm][sn] = __builtin_amdgcn_mfma_f32_16x16x32_bf16(ah[sm], bh[sn], acc[sm][sn], 0, 0, 0); \
            }                                                                        \
    }

#define LOADSET(dst_a, dst_l, dst_b, dst_c, OFF)                                     \
    dst_a = *(const s8v*)(Ahp + (OFF));                                              \
    dst_l = *(const s8v*)(Alp + (OFF));                                              \
    dst_b = *(const s8v*)(Bhp + (OFF));                                              \
    dst_c = *(const s8v*)(Blp + (OFF));

#define WRITESET(src_a, src_l, src_b, src_c, BUF)                                    \
    *(s8v*)&Ash[BUF][wo] = src_a;                                                    \
    *(s8v*)&Asl[BUF][wo] = src_l;                                                    \
    *(s8v*)&Bsh[BUF][wo] = src_b;                                                    \
    *(s8v*)&Bsl[BUF][wo] = src_c;

// ------------- GEMM1 (MFMA): [1344][1024] = A1 x Wconv^T + bconv, out hi/lo bf16 ---
// Preconverted B, 2-deep register prefetch (2 iters of latency cover), 1 barrier/k-step.
__global__ __launch_bounds__(256) void k_gemm1m(const ushortt* __restrict__ Ahi,
                                                const ushortt* __restrict__ Alo,
                                                const ushortt* __restrict__ Bh,
                                                const ushortt* __restrict__ Bl,
                                                const float* __restrict__ bias,
                                                ushortt* __restrict__ Chi,
                                                ushortt* __restrict__ Clo)
{
    const int K = CIN, N = CMID;
    const int NT = K / 32;                          // 16 (even)
    __shared__ __align__(16) ushortt Ash[2][64 * PADK], Asl[2][64 * PADK];
    __shared__ __align__(16) ushortt Bsh[2][64 * PADK], Bsl[2][64 * PADK];
    int tid = threadIdx.x;
    int m0 = blockIdx.y * 64, n0 = blockIdx.x * 64;
    int srow = tid >> 2, sg = tid & 3;
    int lane = tid & 63, wv = tid >> 6;
    int wm = (wv & 1) * 32, wn = (wv >> 1) * 32;
    int quad = lane >> 4, l15 = lane & 15;
    int wo = srow * PADK + sg * 8;

    f4v acc[2][2];
#pragma unroll
    for (int i = 0; i < 2; ++i)
#pragma unroll
        for (int j = 0; j < 2; ++j) acc[i][j] = (f4v){0.f, 0.f, 0.f, 0.f};

    const ushortt* Ahp = Ahi + (size_t)(m0 + srow) * K + sg * 8;
    const ushortt* Alp = Alo + (size_t)(m0 + srow) * K + sg * 8;
    const ushortt* Bhp = Bh  + (size_t)(n0 + srow) * K + sg * 8;
    const ushortt* Blp = Bl  + (size_t)(n0 + srow) * K + sg * 8;

    // prologue: tile0 -> set0 -> LDS[0]; tile1 -> set1 (held in regs)
    s8v a0, l0, b0, c0, a1, l1, b1, c1;
    LOADSET(a0, l0, b0, c0, 0)
    WRITESET(a0, l0, b0, c0, 0)
    LOADSET(a1, l1, b1, c1, 32)
    __syncthreads();

    for (int k = 0; k < NT; k += 2) {
        // even sub-iter: compute tile k (LDS[0]); prefetch tile k+2 -> set0; write tile k+1 -> LDS[1]
        if (k + 2 < NT) { LOADSET(a0, l0, b0, c0, (k + 2) * 32) }
        GEMM_STEP(0)
        WRITESET(a1, l1, b1, c1, 1)                 // tile k+1 (k+1 <= NT-1 always)
        __syncthreads();
        // odd sub-iter: compute tile k+1 (LDS[1]); prefetch tile k+3 -> set1; write tile k+2 -> LDS[0]
        if (k + 3 < NT) { LOADSET(a1, l1, b1, c1, (k + 3) * 32) }
        GEMM_STEP(1)
        if (k + 2 < NT) { WRITESET(a0, l0, b0, c0, 0) }
        __syncthreads();
    }
#pragma unroll
    for (int sm = 0; sm < 2; ++sm)
#pragma unroll
        for (int sn = 0; sn < 2; ++sn)
#pragma unroll
            for (int r = 0; r < 4; ++r) {
                int m = m0 + wm + sm * 16 + quad * 4 + r;
                int n = n0 + wn + sn * 16 + l15;
                float v = acc[sm][sn][r] + bias[n];
                ushortt h = f2bf(v);
                Chi[(size_t)m * N + n] = h;
                Clo[(size_t)m * N + n] = f2bf(v - bf2f(h));
            }
}

// ------------- GEMM2 (MFMA): C2[1344][1280] = A2 x B2pad^T + bias, fp32 out ---
__global__ __launch_bounds__(256) void k_gemm2m(const ushortt* __restrict__ Ahi,
                                                const ushortt* __restrict__ Alo,
                                                const ushortt* __restrict__ Bh,
                                                const ushortt* __restrict__ Bl,
                                                const float* __restrict__ bcls,
                                                const float* __restrict__ breg,
                                                float* __restrict__ C)
{
    const int K = CMID;
    const int NT = K / 32;                          // 32 (even)
    __shared__ __align__(16) ushortt Ash[2][64 * PADK], Asl[2][64 * PADK];
    __shared__ __align__(16) ushortt Bsh[2][64 * PADK], Bsl[2][64 * PADK];
    int tid = threadIdx.x;
    int m0 = blockIdx.y * 64, n0 = blockIdx.x * 64;
    int srow = tid >> 2, sg = tid & 3;
    int lane = tid & 63, wv = tid >> 6;
    int wm = (wv & 1) * 32, wn = (wv >> 1) * 32;
    int quad = lane >> 4, l15 = lane & 15;
    int wo = srow * PADK + sg * 8;

    f4v acc[2][2];
#pragma unroll
    for (int i = 0; i < 2; ++i)
#pragma unroll
        for (int j = 0; j < 2; ++j) acc[i][j] = (f4v){0.f, 0.f, 0.f, 0.f};

    const ushortt* Ahp = Ahi + (size_t)(m0 + srow) * K + sg * 8;
    const ushortt* Alp = Alo + (size_t)(m0 + srow) * K + sg * 8;
    const ushortt* Bhp = Bh  + (size_t)(n0 + srow) * K + sg * 8;
    const ushortt* Blp = Bl  + (size_t)(n0 + srow) * K + sg * 8;

    s8v a0, l0, b0, c0, a1, l1, b1, c1;
    LOADSET(a0, l0, b0, c0, 0)
    WRITESET(a0, l0, b0, c0, 0)
    LOADSET(a1, l1, b1, c1, 32)
    __syncthreads();

    for (int k = 0; k < NT; k += 2) {
        if (k + 2 < NT) { LOADSET(a0, l0, b0, c0, (k + 2) * 32) }
        GEMM_STEP(0)
        WRITESET(a1, l1, b1, c1, 1)
        __syncthreads();
        if (k + 3 < NT) { LOADSET(a1, l1, b1, c1, (k + 3) * 32) }
        GEMM_STEP(1)
        if (k + 2 < NT) { WRITESET(a0, l0, b0, c0, 0) }
        __syncthreads();
    }
#pragma unroll
    for (int sm = 0; sm < 2; ++sm)
#pragma unroll
        for (int sn = 0; sn < 2; ++sn)
#pragma unroll
            for (int r = 0; r < 4; ++r) {
                int m = m0 + wm + sm * 16 + quad * 4 + r;
                int n = n0 + wn + sn * 16 + l15;
                float bb = (n < NCLS) ? bcls[n] : ((n < NCLS + NREGR) ? breg[n - NCLS] : 0.f);
                C[(size_t)m * N2PAD + n] = acc[sm][sn][r] + bb;
            }
}

// ---------------- assemble proposals + scores + start/end + xsel ----------------
__global__ __launch_bounds__(256) void k_assemble(const float* __restrict__ C2,
                                                  const float* __restrict__ AD,
                                                  float* __restrict__ outP,
                                                  float* __restrict__ outS,
                                                  float* __restrict__ startv,
                                                  float* __restrict__ endv,
                                                  float* __restrict__ xsel)
{
    int mb = blockIdx.x;                 // 0..1343
    int b = mb / NEDGE, e = mb - b * NEDGE;
    const float* c2 = C2 + (size_t)mb * N2PAD;
    int tid = threadIdx.x;
    for (int idx = tid; idx < NANG * NPREDD; idx += 256) {
        int a = idx / NPREDD, p = idx - a * NPREDD;
        int prop = e * NANG + a;
        float v;
        if (p < 2) v = c2[a * 2 + p];
        else {
            v = AD[prop * NPREDD + p];
            if (p >= 4) v += c2[NCLS + a * 73 + (p - 4)];
        }
        outP[((size_t)b * NPROPP + prop) * NPREDD + p] = v;
    }
    if (tid < NANG) {
        int a = tid, prop = e * NANG + a;
        float c0 = c2[2 * a], c1 = c2[2 * a + 1];
        float mx = fmaxf(c0, c1);
        float e0 = expf(c0 - mx), e1 = expf(c1 - mx);
        outS[b * NPROPP + prop] = e1 / (e0 + e1);
        float p2 = AD[prop * NPREDD + 2];
        float p4 = AD[prop * NPREDD + 4] + c2[NCLS + a * 73];
        float st = fminf(fmaxf(rintf(p2 * NSTRIPSF), 0.0f), NSTRIPSF);  // round half-to-even
        float en = fminf(fmaxf(st + p4 - 1.0f, 0.0f), NSTRIPSF);
        startv[b * 720 + prop] = st;
        endv[b * 720 + prop] = en;
        int ksi = (int)st;
        // bit-identical to outP[..][5+ksi]
        xsel[b * 720 + prop] = AD[prop * NPREDD + 5 + ksi] + c2[NCLS + a * 73 + ksi + 1];
    }
}

// ---------------- per-batch stable descending rank sort (parallel tiles) -------
__global__ __launch_bounds__(128) void k_sort(const float* __restrict__ scores,
                                              int* __restrict__ order)
{
    int b = blockIdx.x, tile = blockIdx.y, tid = threadIdx.x;
    __shared__ __align__(16) float s[720];
    for (int x = tid; x < 720; x += 128)
        s[x] = (x < NPROPP) ? scores[b * NPROPP + x] : -1e30f;
    __syncthreads();
    int i = tile * 128 + tid;
    if (i >= NPROPP) return;
    float si = s[i];
    int r = 0;
#pragma unroll 4
    for (int j4 = 0; j4 < 720; j4 += 4) {
        float4 v = *(const float4*)&s[j4];
        r += (v.x > si) || (v.x == si && (j4 + 0) < i);
        r += (v.y > si) || (v.y == si && (j4 + 1) < i);
        r += (v.z > si) || (v.z == si && (j4 + 2) < i);
        r += (v.w > si) || (v.w == si && (j4 + 3) < i);
    }
    order[b * 720 + r] = i;
}

// ---------------- suppression matrix, upper-triangle 64x64 tiles only ----------------
// grid (78, NB): blockIdx.x = triangular tile index over (it,jt), jt >= it.
// Below-diagonal words are never written; k_scan synthesizes them as 0.
__global__ __launch_bounds__(256) void k_supmat(const float* __restrict__ outP,
                                                const float* __restrict__ startv,
                                                const float* __restrict__ endv,
                                                const float* __restrict__ xsel,
                                                const int* __restrict__ order,
                                                u64* __restrict__ sup)
{
    int u = blockIdx.x, b = blockIdx.y;
    int it = 0, rem = 12;
    while (u >= rem) { u -= rem; --rem; ++it; }     // row it has 12-it tiles
    int jt = it + u;
    int i0 = it * 64, j0 = jt * 64;
    int tid = threadIdx.x;
    __shared__ float SI[64], EI[64], XI[64];
    __shared__ float SJ[64], EJ[64], XJ[64];
    __shared__ int   OI[64], OJ[64];
    if (tid < 128) {
        int side = tid >> 6, q = tid & 63;
        int pos = (side ? j0 : i0) + q;
        int o = (pos < NPROPP) ? order[b * 720 + pos] : -1;
        float st = (o >= 0) ? startv[b * 720 + o] : 0.f;
        float en = (o >= 0) ? endv[b * 720 + o] : -2.f;   // cnt<=-1 -> never suppress
        float xv = (o >= 0) ? xsel[b * 720 + o] : 0.f;
        if (!side) { SI[q] = st; EI[q] = en; XI[q] = xv; OI[q] = o; }
        else       { SJ[q] = st; EJ[q] = en; XJ[q] = xv; OJ[q] = o; }
    }
    __syncthreads();
    int lane = tid & 63, w = tid >> 6;
    int j = j0 + lane;
    float sj = SJ[lane], ej = EJ[lane], xj = XJ[lane];
    const float* basexs = outP + (size_t)b * NPROPP * NPREDD + 5;
#pragma unroll 1
    for (int rep = 0; rep < 16; ++rep) {
        int iloc = w * 16 + rep;
        int il = i0 + iloc;
        float si = SI[iloc], ei = EI[iloc];
        float s = fmaxf(si, sj), e = fminf(ei, ej);
        float cnt = e - s + 1.0f;
        bool sp = false;
        if (cnt > 0.f) {
            if (e < s) {
                sp = true;                               // empty range: dist = 0
            } else {
                int ks = (int)s, ke = (int)e;
                if (si == sj && ke == ks) {
                    sp = (fabsf(XI[iloc] - xj) / fmaxf(cnt, 1.0f)) < 15.0f;
                } else {                                  // rare general case
                    const float* xi  = basexs + (size_t)OI[iloc] * NPREDD;
                    const float* xjp = basexs + (size_t)OJ[lane] * NPREDD;
                    float sum = 0.f;
                    for (int k = ks; k <= ke; ++k)
                        sum += fabsf(xi[k] - xjp[k]);
                    sp = (sum / fmaxf(cnt, 1.0f)) < 15.0f;
                }
            }
        }
        bool valid = (il < NPROPP) && (j < NPROPP) && (j > il);
        u64 msk = __ballot(valid && sp);
        if (lane == 0 && il < NPROPP)
            sup[((size_t)b * NPROPP + il) * 12 + jt] = msk;
    }
}

// ---------------- NMS via Jacobi fixpoint (per batch, 256 threads) ----------------
// Greedy NMS keep is the UNIQUE fixpoint of keep[i] = !exists j<i: keep[j]&sup[j][i]
// (proof: induction on i). Iterate K <- valid & ~OR{row_j : K[j]} with full-width
// parallel sweeps until K is unchanged; K^t==K^{t-1} => fixpoint => exact greedy.
// Words t < (row>>6) are structurally zero (supmat never writes them): synthesized.
// NOTE: keep the plain butterfly reduce — sweep time is bounded by the two
// __syncthreads per sweep, not the shfls; the "adaptive" variant (R7) cost +8.7us
// via extra live registers + divergent branch. Do not re-add.
__global__ __launch_bounds__(256) void k_scan(const u64* __restrict__ sup,
                                              const int* __restrict__ order,
                                              float* __restrict__ keep_out)
{
    int b = blockIdx.x, tid = threadIdx.x;
    int lane = tid & 63;
    __shared__ u64 K[12], NS[12];
    __shared__ int changed;
    const u64* base = sup + (size_t)b * NPROPP * 12;

    int r0 = tid, r1 = tid + 256, r2 = tid + 512;
    int t0 = r0 >> 6, t1 = r1 >> 6, t2 = r2 >> 6;   // first nonzero word per row
    u64 row0[12], row1[12], row2[12];
#pragma unroll
    for (int t = 0; t < 12; ++t) {
        row0[t] = (t >= t0) ? base[(size_t)r0 * 12 + t] : 0ull;    // r0 < 714 always
        row1[t] = (r1 < NPROPP && t >= t1) ? base[(size_t)r1 * 12 + t] : 0ull;
        row2[t] = (r2 < NPROPP && t >= t2) ? base[(size_t)r2 * 12 + t] : 0ull;
    }
    if (tid < 12) {
        K[tid] = (tid < 11) ? ~0ull : ((1ull << (NPROPP - 704)) - 1ull);  // valid mask
        NS[tid] = 0ull;
    }
    __syncthreads();

    for (int sweep = 0; sweep < 720; ++sweep) {
        u64 m0 = 0ull - ((K[r0 >> 6] >> (r0 & 63)) & 1ull);
        u64 m1 = (r1 < NPROPP) ? (0ull - ((K[r1 >> 6] >> (r1 & 63)) & 1ull)) : 0ull;
        u64 m2 = (r2 < NPROPP) ? (0ull - ((K[r2 >> 6] >> (r2 & 63)) & 1ull)) : 0ull;
        unsigned lo[12], hi[12];
#pragma unroll
        for (int t = 0; t < 12; ++t) {
            u64 a = (row0[t] & m0) | (row1[t] & m1) | (row2[t] & m2);
            lo[t] = (unsigned)a;
            hi[t] = (unsigned)(a >> 32);
        }
#pragma unroll
        for (int s = 1; s < 64; s <<= 1) {
#pragma unroll
            for (int t = 0; t < 12; ++t) {
                lo[t] |= __shfl_xor(lo[t], s, 64);
                hi[t] |= __shfl_xor(hi[t], s, 64);
            }
        }
        if (tid == 0) changed = 0;
        if (lane == 0) {
#pragma unroll
            for (int t = 0; t < 12; ++t)
                atomicOr(&NS[t], ((u64)hi[t] << 32) | (u64)lo[t]);
        }
        __syncthreads();
        if (tid < 12) {
            u64 valid = (tid < 11) ? ~0ull : ((1ull << (NPROPP - 704)) - 1ull);
            u64 nk = valid & ~NS[tid];
            if (nk != K[tid]) changed = 1;   // benign race: same value
            K[tid] = nk;
            NS[tid] = 0ull;
        }
        __syncthreads();
        if (!changed) break;
    }
    if (r0 < NPROPP)
        keep_out[b * NPROPP + order[b * 720 + r0]] =
            ((K[r0 >> 6] >> (r0 & 63)) & 1ull) ? 1.f : 0.f;
    if (r1 < NPROPP)
        keep_out[b * NPROPP + order[b * 720 + r1]] =
            ((K[r1 >> 6] >> (r1 & 63)) & 1ull) ? 1.f : 0.f;
    if (r2 < NPROPP)
        keep_out[b * NPROPP + order[b * 720 + r2]] =
            ((K[r2 >> 6] >> (r2 & 63)) & 1ull) ? 1.f : 0.f;
}

extern "C" void kernel_launch(void* const* d_in, const int* in_sizes, int n_in,
                              void* d_out, int out_size, void* d_ws, size_t ws_size,
                              hipStream_t stream)
{
    const float* feat  = (const float*)d_in[0];
    const float* Wconv = (const float*)d_in[1];
    const float* bconv = (const float*)d_in[2];
    const float* Wcls  = (const float*)d_in[3];
    const float* bcls  = (const float*)d_in[4];
    const float* Wreg  = (const float*)d_in[5];
    const float* breg  = (const float*)d_in[6];
    const float* AD    = (const float*)d_in[8];   // anchors_anchor_dim (714,77)

    float* out  = (float*)d_out;
    float* outP = out;                                     // proposals 32*714*77
    float* outK = out + (size_t)NB * NPROPP * NPREDD;      // keep mask  32*714
    float* outS = outK + (size_t)NB * NPROPP;              // scores     32*714

    float* ws = (float*)d_ws;
    // [0, 688128) floats: A1hi/A1lo bf16 (dead after gemm1) -> NMS scratch later
    ushortt* A1hi = (ushortt*)ws;                          // 688128 bf16
    ushortt* A1lo = (ushortt*)(ws + 344064);               // 688128 bf16
    ushortt* A2hi = (ushortt*)(ws + 688128);               // 1344*1024 bf16
    ushortt* A2lo = (ushortt*)(ws + 1376256);              // 1344*1024 bf16
    float*   C2   = ws + 2064384;                          // 1344*1280 fp32, ends 3784704
    // preconverted weights (live through gemms, past C2):
    ushortt* B1h  = (ushortt*)(ws + 3784704);              // 1024*512 bf16
    ushortt* B1l  = (ushortt*)(ws + 4046848);
    ushortt* B2h  = (ushortt*)(ws + 4308992);              // 1280*1024 bf16
    ushortt* B2l  = (ushortt*)(ws + 4964352);              // ends @5619712 floats
    // NMS scratch overlays dead A1 region:
    float* startv = ws;                                    // 32*720 floats
    float* endv   = ws + 23040;                            // 32*720 floats
    int*   order  = (int*)(ws + 46080);                    // 32*720 ints
    u64*   sup    = (u64*)(ws + 69120);                    // 32*714*12 u64, ends @617472
    float* xsel   = ws + 617472;                           // 32*720 floats, ends @640512

    k_prep        <<<dim3(2304),       dim3(256), 0, stream>>>(feat, A1hi, A1lo,
                                                               Wconv, B1h, B1l,
                                                               Wcls, Wreg, B2h, B2l);
    k_gemm1m      <<<dim3(16, 21),     dim3(256), 0, stream>>>(A1hi, A1lo, B1h, B1l, bconv, A2hi, A2lo);
    k_gemm2m      <<<dim3(20, 21),     dim3(256), 0, stream>>>(A2hi, A2lo, B2h, B2l, bcls, breg, C2);
    k_assemble    <<<dim3(MTOT),       dim3(256), 0, stream>>>(C2, AD, outP, outS, startv, endv, xsel);
    k_sort        <<<dim3(NB, 6),      dim3(128), 0, stream>>>(outS, order);
    k_supmat      <<<dim3(78, NB),     dim3(256), 0, stream>>>(outP, startv, endv, xsel, order, sup);
    k_scan        <<<dim3(NB),         dim3(256), 0, stream>>>(sup, order, outK);
}